// Round 7
// baseline (20820.032 us; speedup 1.0000x reference)
//
#include <hip/hip_runtime.h>

// B=64, T=256, H=1024, L=6. Cell: h = tanh((prev + h_old) @ W^T + b1 + b2).
// v7 = v6 (reg-stationary W, relaxed-atomic comm) + two latency fixes:
//  1. FLAG PADDING: each barrier flag gets its own 128-B line. v6 packed all
//     32 group flags into ONE line -> 32 write-through stores serialized on
//     the line (~10us/cell barrier, the dominant cost). partial[] similarly
//     re-laid-out so each block writes a private 32-B sector.
//  2. h_old PREFETCH: next cell's h_old is stable 5+ barriers before use;
//     load it into regs during the current FMA loop. Post-barrier critical
//     path is only the prev-vector load.

#define BB 64
#define TT 256
#define HH 1024
#define LL 6
#define NG 8     // groups, GB batches each
#define GB 8     // batches per group
#define NQ 32    // blocks (j-slices) per group
#define SJ 32    // j rows per block
#define NTH 256
#define FLAG_PAD 32                                    // 32 uints = 128 B/flag

#define HSTATE_FLOATS (2ull * BB * LL * HH)            // parity x b x l x k
#define FLAGS_OFF   (HSTATE_FLOATS * 4)                // 3,145,728 B
#define FLAGS_BYTES ((size_t)NG * NQ * FLAG_PAD * 4)   // 32 KB
#define PARTIAL_OFF (FLAGS_OFF + FLAGS_BYTES)          // [2][NG][NQ][GB] floats

__device__ __forceinline__ float2 aload2(const float* p) {
    unsigned long long u = __hip_atomic_load((const unsigned long long*)p,
                                             __ATOMIC_RELAXED, __HIP_MEMORY_SCOPE_AGENT);
    union { unsigned long long u; float2 f; } c; c.u = u; return c.f;
}
__device__ __forceinline__ float aload1(const float* p) {
    return __hip_atomic_load(p, __ATOMIC_RELAXED, __HIP_MEMORY_SCOPE_AGENT);
}
__device__ __forceinline__ void astore1(float* p, float v) {
    __hip_atomic_store(p, v, __ATOMIC_RELAXED, __HIP_MEMORY_SCOPE_AGENT);
}

__global__ void __launch_bounds__(NTH, 1)
rnn_kernel(const float* __restrict__ h0,
           const float* __restrict__ Whh,
           const float* __restrict__ bias_ih,
           const float* __restrict__ bias_bh,
           const float* __restrict__ w_out,
           const float* __restrict__ b_out,
           float* hstate, unsigned* flags, float* partial,
           float* __restrict__ d_out)
{
    __shared__ float4 s4[GB * 256];       // 32 KB: s[bb][k4]
    __shared__ float  pred[4][SJ][10];    //  5 KB: per-wave partials (pad 10)

    const int tid = threadIdx.x;
    const int g   = blockIdx.x & 7;       // group
    const int q   = blockIdx.x >> 3;      // j-slice 0..31
    const int gb  = g * GB;
    const int jl  = tid & 31;
    const int ks  = tid >> 5;             // k-slice 0..7
    const int wv  = tid >> 6;             // wave 0..3
    const int jg  = q * SJ + jl;

    // ---- W -> registers (one-time)
    float4 wreg[32];
    {
        const float4* wrow = (const float4*)(Whh + (size_t)jg * HH) + ks * 32;
#pragma unroll
        for (int r = 0; r < 32; ++r) wreg[r] = wrow[r];
    }

    const float bias_j = bias_ih[jg] + bias_bh[jg];
    const float wout_j = w_out[jg];
    const float bout   = b_out[0];

    // ---- init parity-1 hstate (atomic stores: cross-block visible)
    {
        int bb = tid >> 5, k = q * SJ + (tid & 31);
#pragma unroll
        for (int l = 0; l < LL; ++l)
            astore1(&hstate[(((size_t)1 * BB + gb + bb) * LL + l) * HH + k],
                    h0[((size_t)l * BB + gb + bb) * HH + k]);
    }

    unsigned* gflags = flags + (size_t)g * NQ * FLAG_PAD;
    unsigned barno = 0;

    auto gbar = [&]() {
        ++barno;
        asm volatile("s_waitcnt vmcnt(0)" ::: "memory");  // this wave's stores done
        __syncthreads();                                  // => all waves' stores done
        if (tid == 0)
            __hip_atomic_store(gflags + (size_t)q * FLAG_PAD, barno,
                               __ATOMIC_RELAXED, __HIP_MEMORY_SCOPE_AGENT);
        if (tid < 64) {                                   // wave-0 vector poll
            for (int w = 0; w < 200000; ++w) {
                unsigned v = (tid < NQ)
                    ? __hip_atomic_load(gflags + (size_t)tid * FLAG_PAD,
                                        __ATOMIC_RELAXED, __HIP_MEMORY_SCOPE_AGENT)
                    : barno;
                if (!~__ballot(v >= barno)) break;
                __builtin_amdgcn_s_sleep(1);
            }
        }
        __syncthreads();
        asm volatile("" ::: "memory");                    // no hoisting of data loads
    };

    gbar();   // publish init

    // ---- prefetch h_old for cell (t=0, l=0): parity 1, layer 0
    float2 ha[GB][2];
    {
        const float* baseH = hstate + (((size_t)1 * BB + gb) * LL + 0) * HH;
#pragma unroll
        for (int r = 0; r < GB; ++r) {
            const float* H = baseH + (size_t)r * LL * HH + tid * 4;
            ha[r][0] = aload2(H);  ha[r][1] = aload2(H + 2);
        }
    }

    for (int t = 0; t < TT; ++t) {
        const int pw = t & 1, pr = pw ^ 1;
        for (int l = 0; l < LL; ++l) {
            const int lp = (l == 0) ? (LL - 1) : (l - 1);
            const int pp = (l == 0) ? pr : pw;   // prev-chain parity

            // ---- post-barrier critical loads: prev only
            const float* baseP = hstate + (((size_t)pp * BB + gb) * LL + lp) * HH;
            float2 pa[GB][2];
#pragma unroll
            for (int r = 0; r < GB; ++r) {       // r = batch, tid = k4 (coalesced)
                const float* P = baseP + (size_t)r * LL * HH + tid * 4;
                pa[r][0] = aload2(P);  pa[r][1] = aload2(P + 2);
            }
#pragma unroll
            for (int r = 0; r < GB; ++r)
                s4[r * 256 + tid] = make_float4(pa[r][0].x + ha[r][0].x,
                                                pa[r][0].y + ha[r][0].y,
                                                pa[r][1].x + ha[r][1].x,
                                                pa[r][1].y + ha[r][1].y);
            __syncthreads();

            // ---- prefetch h_old for NEXT cell (stable; overlaps FMA below)
            {
                const int nl  = (l == LL - 1) ? 0  : l + 1;
                const int npr = (l == LL - 1) ? pw : pr;
                const float* baseHn = hstate + (((size_t)npr * BB + gb) * LL + nl) * HH;
#pragma unroll
                for (int r = 0; r < GB; ++r) {
                    const float* H = baseHn + (size_t)r * LL * HH + tid * 4;
                    ha[r][0] = aload2(H);  ha[r][1] = aload2(H + 2);
                }
            }

            // ---- 1024 reg-reg FMA, 8 independent accumulator chains
            float acc[GB];
#pragma unroll
            for (int b = 0; b < GB; ++b) acc[b] = 0.f;
            const float4* xbase = s4 + ks * 32;
#pragma unroll
            for (int b = 0; b < GB; ++b) {
#pragma unroll
                for (int k4 = 0; k4 < 32; ++k4) {
                    float4 x = xbase[b * 256 + k4];   // broadcast LDS read
                    float4 w = wreg[k4];              // register-resident W
                    acc[b] = fmaf(w.x, x.x, fmaf(w.y, x.y,
                             fmaf(w.z, x.z, fmaf(w.w, x.w, acc[b]))));
                }
            }

            // ---- k-reduce: shfl merge ks pairs, then 4 waves via LDS
#pragma unroll
            for (int b = 0; b < GB; ++b) acc[b] += __shfl_xor(acc[b], 32);
            if ((tid & 63) < 32) {
#pragma unroll
                for (int b = 0; b < GB; ++b) pred[wv][jl][b] = acc[b];
            }
            __syncthreads();

            const int bb = tid >> 5;     // thread (jl, bb) owns output
            float ysum = pred[0][jl][bb] + pred[1][jl][bb]
                       + pred[2][jl][bb] + pred[3][jl][bb];
            float y = tanhf(ysum + bias_j);
            astore1(&hstate[(((size_t)pw * BB + gb + bb) * LL + l) * HH + jg], y);

            if (l == LL - 1) {
                float c = y * wout_j;
#pragma unroll
                for (int off = 16; off; off >>= 1) c += __shfl_down(c, off, 32);
                if (jl == 0)   // private 32-B sector per block: no line sharing
                    astore1(&partial[(((size_t)pw * NG + g) * NQ + q) * GB + bb], c);
            }
            if (t == TT - 1)
                d_out[(size_t)BB * TT + ((size_t)l * BB + gb + bb) * HH + jg] = y;

            gbar();

            if (l == LL - 1 && q == 0 && tid < GB) {
                int bo = gb + tid;
                float s = bout;
#pragma unroll
                for (int qq = 0; qq < NQ; ++qq)
                    s += aload1(&partial[(((size_t)pw * NG + g) * NQ + qq) * GB + tid]);
                d_out[(size_t)bo * TT + t] = s;    // out[b, t, 0]
            }
        }
    }
}

extern "C" void kernel_launch(void* const* d_in, const int* in_sizes, int n_in,
                              void* d_out, int out_size, void* d_ws, size_t ws_size,
                              hipStream_t stream) {
    // inputs: 0:x(unused) 1:h0 2:weight_ih(unused) 3:bias_ih 4:weight_hh 5:bias_bh 6:w_out 7:b_out
    const float* h0      = (const float*)d_in[1];
    const float* bias_ih = (const float*)d_in[3];
    const float* Whh     = (const float*)d_in[4];
    const float* bias_bh = (const float*)d_in[5];
    const float* w_out   = (const float*)d_in[6];
    const float* b_out   = (const float*)d_in[7];

    float*    hstate  = (float*)d_ws;
    unsigned* flags   = (unsigned*)((char*)d_ws + FLAGS_OFF);
    float*    partial = (float*)((char*)d_ws + PARTIAL_OFF);

    hipMemsetAsync(flags, 0, FLAGS_BYTES, stream);   // fresh monotonic flags per launch
    rnn_kernel<<<NG * NQ, NTH, 0, stream>>>(h0, Whh, bias_ih, bias_bh,
                                            w_out, b_out, hstate, flags, partial,
                                            (float*)d_out);
}

// Round 8
// 18262.172 us; speedup vs baseline: 1.1401x; 1.1401x over previous
//
#include <hip/hip_runtime.h>

// B=64, T=256, H=1024, L=6. Cell: h = tanh((prev + h_old) @ W^T + b1 + b2).
// v8: BARRIER-FREE dataflow. 8 groups (8 batches) x 32 j-slice blocks, W in
// VGPRs (128/thread). Synchronization is embedded in the data: y in (-1,1)
// is stored as y + o(t), o(t) = 8 + 8*((t>>1)&1); h0 init stored as h0 + 64.
// Consumers poll-load (relaxed agent atomics, MALL-coherent) and accept a
// word when |v - o_expected| <= tol. Tags disambiguate slot occupants (t vs
// t-2), init vs real, and scrub poison. v - o is exact (Sterbenz). No flags,
// no vmcnt drains, no max-of-32 barrier tail. hstate scrubbed per launch
// (cross-launch tag ABA). All spins bounded -> no hangs, failures visible.

#define BB 64
#define TT 256
#define HH 1024
#define LL 6
#define NG 8     // groups, GB batches each
#define GB 8     // batches per group
#define NQ 32    // blocks (j-slices) per group
#define SJ 32    // j rows per block
#define NTH 256
#define MAXIT (1 << 22)

#define HSTATE_BYTES (2ull * BB * LL * HH * 4)   // [parity][b][l][k], 3 MB

static __device__ __forceinline__ float2 aload2(const float* p) {
    unsigned long long u = __hip_atomic_load((const unsigned long long*)p,
        __ATOMIC_RELAXED, __HIP_MEMORY_SCOPE_AGENT);
    union { unsigned long long u; float2 f; } c; c.u = u; return c.f;
}
static __device__ __forceinline__ void astore1(float* p, float v) {
    __hip_atomic_store(p, v, __ATOMIC_RELAXED, __HIP_MEMORY_SCOPE_AGENT);
}
static __device__ __forceinline__ bool ok2(float2 v, float tag, float tol) {
    return fabsf(v.x - tag) <= tol && fabsf(v.y - tag) <= tol;
}

__global__ void __launch_bounds__(NTH, 1)
rnn_kernel(const float* __restrict__ h0,
           const float* __restrict__ Whh,
           const float* __restrict__ bias_ih,
           const float* __restrict__ bias_bh,
           const float* __restrict__ w_out,
           const float* __restrict__ b_out,
           float* hstate,
           float* __restrict__ d_out)
{
    __shared__ float4 s4[GB * 256];        // 32 KB: s[bb][k4]
    __shared__ float  pred[2][4][SJ][10];  // 10 KB: per-wave partials, cell-parity dbuf
    __shared__ float  outred[2][4];        // out-projection wave partials

    const int tid = threadIdx.x;
    const int g   = blockIdx.x & 7;        // group
    const int q   = blockIdx.x >> 3;       // j-slice 0..31
    const int gb  = g * GB;
    const int jl  = tid & 31;
    const int ks  = tid >> 5;              // k-slice 0..7
    const int wv  = tid >> 6;              // wave 0..3
    const int jg  = q * SJ + jl;

    // ---- W -> registers (one-time)
    float4 wreg[32];
    {
        const float4* wrow = (const float4*)(Whh + (size_t)jg * HH) + ks * 32;
#pragma unroll
        for (int r = 0; r < 32; ++r) wreg[r] = wrow[r];
    }

    const float  bias_j = bias_ih[jg] + bias_bh[jg];
    const float  wout_j = w_out[jg];
    const float4 wo     = ((const float4*)w_out)[tid];
    const float  bout   = b_out[0];
    (void)wout_j;

    // ---- init parity-1 hstate, tagged +64 (consumers validate; no barrier)
    {
        int bb = tid >> 5, k = q * SJ + (tid & 31);
#pragma unroll
        for (int l = 0; l < LL; ++l)
            astore1(&hstate[(((size_t)1 * BB + gb + bb) * LL + l) * HH + k],
                    h0[((size_t)l * BB + gb + bb) * HH + k] + 64.0f);
    }

    for (int t = 0; t < TT; ++t) {
        const int   pw   = t & 1, pr = pw ^ 1;
        const float tagW = 8.0f + 8.0f * (float)((t >> 1) & 1);       // o(t)
        const float tagO = 8.0f + 8.0f * (float)(((t - 1) >> 1) & 1); // o(t-1)
        const float tagH = (t == 0) ? 64.0f : tagO;
        const float tolH = (t == 0) ? 16.0f : 1.0f;

        for (int l = 0; l < LL; ++l) {
            const int   lp   = (l == 0) ? (LL - 1) : (l - 1);
            const int   pp   = (l == 0) ? pr : pw;        // prev-chain parity
            const float tagP = (l == 0) ? tagH : tagW;
            const float tolP = (l == 0) ? tolH : 1.0f;
            const int   cp   = l & 1;                     // cell parity (pred dbuf)

            // ---- validated gather of prev + h_old (issue all, re-poll stale)
            const float* baseP = hstate + (((size_t)pp * BB + gb) * LL + lp) * HH + (tid << 2);
            const float* baseH = hstate + (((size_t)pr * BB + gb) * LL + l ) * HH + (tid << 2);
            float2 pa0[GB], pa1[GB], ha0[GB], ha1[GB];
#pragma unroll
            for (int r = 0; r < GB; ++r) {
                const float* P = baseP + (size_t)r * LL * HH;
                const float* H = baseH + (size_t)r * LL * HH;
                pa0[r] = aload2(P);  pa1[r] = aload2(P + 2);
                ha0[r] = aload2(H);  ha1[r] = aload2(H + 2);
            }
            unsigned bad = 0;
#pragma unroll
            for (int r = 0; r < GB; ++r) {
                if (!ok2(pa0[r], tagP, tolP)) bad |= 1u << (4 * r);
                if (!ok2(pa1[r], tagP, tolP)) bad |= 2u << (4 * r);
                if (!ok2(ha0[r], tagH, tolH)) bad |= 4u << (4 * r);
                if (!ok2(ha1[r], tagH, tolH)) bad |= 8u << (4 * r);
            }
            for (int it = 0; bad && it < MAXIT; ++it) {
                __builtin_amdgcn_s_sleep(1);
#pragma unroll
                for (int r = 0; r < GB; ++r) {
                    const float* P = baseP + (size_t)r * LL * HH;
                    const float* H = baseH + (size_t)r * LL * HH;
                    if (bad & (1u << (4 * r))) { pa0[r] = aload2(P);     if (ok2(pa0[r], tagP, tolP)) bad &= ~(1u << (4 * r)); }
                    if (bad & (2u << (4 * r))) { pa1[r] = aload2(P + 2); if (ok2(pa1[r], tagP, tolP)) bad &= ~(2u << (4 * r)); }
                    if (bad & (4u << (4 * r))) { ha0[r] = aload2(H);     if (ok2(ha0[r], tagH, tolH)) bad &= ~(4u << (4 * r)); }
                    if (bad & (8u << (4 * r))) { ha1[r] = aload2(H + 2); if (ok2(ha1[r], tagH, tolH)) bad &= ~(8u << (4 * r)); }
                }
            }

            // ---- s = (prev - tagP) + (h_old - tagH); both subtractions exact
#pragma unroll
            for (int r = 0; r < GB; ++r)
                s4[r * 256 + tid] = make_float4(
                    (pa0[r].x - tagP) + (ha0[r].x - tagH),
                    (pa0[r].y - tagP) + (ha0[r].y - tagH),
                    (pa1[r].x - tagP) + (ha1[r].x - tagH),
                    (pa1[r].y - tagP) + (ha1[r].y - tagH));

            // ---- output projection for (t-1): prev at l==0 IS y(t-1, 5)
            if (l == 0 && t > 0 && q < GB) {
                float val = 0.f;
#pragma unroll
                for (int r = 0; r < GB; ++r) if (r == q)
                    val = (pa0[r].x - tagP) * wo.x + (pa0[r].y - tagP) * wo.y
                        + (pa1[r].x - tagP) * wo.z + (pa1[r].y - tagP) * wo.w;
#pragma unroll
                for (int off = 32; off; off >>= 1) val += __shfl_down(val, off, 64);
                if ((tid & 63) == 0) outred[t & 1][wv] = val;
            }
            __syncthreads();

            if (l == 0 && t > 0 && q < GB && tid == 0)
                d_out[(size_t)(gb + q) * TT + (t - 1)] =
                    outred[t & 1][0] + outred[t & 1][1] +
                    outred[t & 1][2] + outred[t & 1][3] + bout;

            // ---- 1024 reg-reg FMA, 8 independent accumulator chains
            float acc[GB];
#pragma unroll
            for (int b = 0; b < GB; ++b) acc[b] = 0.f;
            const float4* xbase = s4 + ks * 32;
#pragma unroll
            for (int b = 0; b < GB; ++b) {
#pragma unroll
                for (int k4 = 0; k4 < 32; ++k4) {
                    float4 x = xbase[b * 256 + k4];   // broadcast LDS read
                    float4 w = wreg[k4];              // register-resident W
                    acc[b] = fmaf(w.x, x.x, fmaf(w.y, x.y,
                             fmaf(w.z, x.z, fmaf(w.w, x.w, acc[b]))));
                }
            }

            // ---- k-reduce: shfl merge ks pairs, then 4 waves via LDS (dbuf)
#pragma unroll
            for (int b = 0; b < GB; ++b) acc[b] += __shfl_xor(acc[b], 32);
            if ((tid & 63) < 32) {
#pragma unroll
                for (int b = 0; b < GB; ++b) pred[cp][wv][jl][b] = acc[b];
            }
            __syncthreads();

            const int bb = tid >> 5;     // thread (jl, bb) owns output
            float ysum = pred[cp][0][jl][bb] + pred[cp][1][jl][bb]
                       + pred[cp][2][jl][bb] + pred[cp][3][jl][bb];
            float y = tanhf(ysum + bias_j);
            astore1(&hstate[(((size_t)pw * BB + gb + bb) * LL + l) * HH + jg],
                    y + tagW);           // tagged publish: store IS the flag

            if (t == TT - 1)
                d_out[(size_t)BB * TT + ((size_t)l * BB + gb + bb) * HH + jg] = y;
        }
    }

    // ---- epilogue: out[b, 255] from y(255, 5) (parity 1, tag o(255)=16)
    if (q < GB) {
        const float* P = hstate + (((size_t)1 * BB + gb + q) * LL + 5) * HH + (tid << 2);
        float2 a0 = aload2(P), a1 = aload2(P + 2);
        for (int it = 0; (!ok2(a0, 16.0f, 1.0f) || !ok2(a1, 16.0f, 1.0f)) && it < MAXIT; ++it) {
            __builtin_amdgcn_s_sleep(1);
            a0 = aload2(P);  a1 = aload2(P + 2);
        }
        float val = (a0.x - 16.0f) * wo.x + (a0.y - 16.0f) * wo.y
                  + (a1.x - 16.0f) * wo.z + (a1.y - 16.0f) * wo.w;
#pragma unroll
        for (int off = 32; off; off >>= 1) val += __shfl_down(val, off, 64);
        if ((tid & 63) == 0) outred[0][wv] = val;
        __syncthreads();
        if (tid == 0)
            d_out[(size_t)(gb + q) * TT + (TT - 1)] =
                outred[0][0] + outred[0][1] + outred[0][2] + outred[0][3] + bout;
    }
}

extern "C" void kernel_launch(void* const* d_in, const int* in_sizes, int n_in,
                              void* d_out, int out_size, void* d_ws, size_t ws_size,
                              hipStream_t stream) {
    // inputs: 0:x(unused) 1:h0 2:weight_ih(unused) 3:bias_ih 4:weight_hh 5:bias_bh 6:w_out 7:b_out
    const float* h0      = (const float*)d_in[1];
    const float* bias_ih = (const float*)d_in[3];
    const float* Whh     = (const float*)d_in[4];
    const float* bias_bh = (const float*)d_in[5];
    const float* w_out   = (const float*)d_in[6];
    const float* b_out   = (const float*)d_in[7];

    float* hstate = (float*)d_ws;

    // scrub tags every launch: stale cross-launch tags would alias (ABA)
    hipMemsetAsync(hstate, 0, HSTATE_BYTES, stream);
    rnn_kernel<<<NG * NQ, NTH, 0, stream>>>(h0, Whh, bias_ih, bias_bh,
                                            w_out, b_out, hstate, (float*)d_out);
}